// Round 1
// baseline (1071.253 us; speedup 1.0000x reference)
//
#include <hip/hip_runtime.h>
#include <stdint.h>

#define NUM_CLASS 100000
#define EMB 512
#define BATCH 1024
#define S_SCALE 64.0f
#define T_HARD 1.2f            // T + 1
#define COS_M   0.8775825618903728f
#define SIN_M   0.479425538604203f
#define THETA_C (-0.8775825618903728f)   // cos(pi - M)
#define SINMM   0.2397127693021015f      // sin(pi - M) * M
#define COS_M1  0.9800665778412416f
#define SIN_M1  0.19866933079506122f
#define SINMM1  (-0.039733866159012244f) // sin(-M1) * M1

#define NCOL_TILES 782
#define GRID_X (8 * NCOL_TILES)          // 6256 blocks

typedef __attribute__((ext_vector_type(8))) short bf16x8;
typedef __attribute__((ext_vector_type(4))) float floatx4;

__device__ __forceinline__ unsigned short f2bf(float f) {
    union { float f; unsigned u; } v; v.f = f;
    unsigned r = v.u + 0x7fffu + ((v.u >> 16) & 1u);
    return (unsigned short)(r >> 16);
}
__device__ __forceinline__ float blo(unsigned u) {
    union { unsigned v; float f; } c; c.v = u << 16; return c.f;
}
__device__ __forceinline__ float bhi(unsigned u) {
    union { unsigned v; float f; } c; c.v = u & 0xffff0000u; return c.f;
}
__device__ __forceinline__ void load16(const unsigned short* g, unsigned short* l) {
    __builtin_amdgcn_global_load_lds(
        (const __attribute__((address_space(1))) void*)g,
        (__attribute__((address_space(3))) void*)l, 16, 0, 0);
}

// ---- Kernel 1: normalize embeddings -> bf16 ----
__global__ void k_embed(const float* __restrict__ emb, unsigned short* __restrict__ ne) {
    int row = blockIdx.x;            // 1024
    int t = threadIdx.x;             // 256, 2 floats each
    float2 v = ((const float2*)(emb + row * EMB))[t];
    float ss = v.x * v.x + v.y * v.y;
    __shared__ float red[4];
    for (int off = 32; off; off >>= 1) ss += __shfl_down(ss, off);
    if ((t & 63) == 0) red[t >> 6] = ss;
    __syncthreads();
    float inv = rsqrtf(red[0] + red[1] + red[2] + red[3]);
    unsigned b0 = f2bf(v.x * inv), b1 = f2bf(v.y * inv);
    ((unsigned*)(ne + row * EMB))[t] = b0 | (b1 << 16);
}

// ---- Kernel 2: target logits from RAW fp32 weights (one wave per row) ----
// tl = (ne . w) / |w|  (normalization deferred, matches GEMM's epilogue)
__global__ void k_tl(const unsigned short* __restrict__ ne, const float* __restrict__ w,
                     const int* __restrict__ labels, float* __restrict__ ftl, float* __restrict__ ftl1) {
    int b = blockIdx.x * 4 + (threadIdx.x >> 6);
    int L = threadIdx.x & 63;
    int lab = labels[b];
    uint4 ua = *(const uint4*)(ne + (size_t)b * EMB + L * 8);
    const float4* wp = (const float4*)(w + (size_t)lab * EMB + L * 8);
    float4 w0 = wp[0], w1 = wp[1];
    float ss = w0.x*w0.x + w0.y*w0.y + w0.z*w0.z + w0.w*w0.w
             + w1.x*w1.x + w1.y*w1.y + w1.z*w1.z + w1.w*w1.w;
    float s = blo(ua.x)*w0.x + bhi(ua.x)*w0.y + blo(ua.y)*w0.z + bhi(ua.y)*w0.w
            + blo(ua.z)*w1.x + bhi(ua.z)*w1.y + blo(ua.w)*w1.z + bhi(ua.w)*w1.w;
    for (int off = 32; off; off >>= 1) {
        s  += __shfl_down(s, off);
        ss += __shfl_down(ss, off);
    }
    if (L == 0) {
        float tl = s * rsqrtf(ss);
        tl = fminf(1.0f, fmaxf(-1.0f, tl));
        float st = sqrtf(fmaxf(0.0f, 1.0f - tl * tl));
        float cos_tm  = tl * COS_M  - st * SIN_M;
        float cos_tm1 = tl * COS_M1 - st * SIN_M1;
        float f  = (tl > THETA_C)  ? cos_tm  : (tl - SINMM);
        float f1 = (tl <= COS_M1)  ? cos_tm1 : (tl + SINMM1);
        ftl[b] = f;
        ftl1[b] = f1;
    }
}

// ---- Kernel 3: fused bf16 MFMA GEMM 128x128 + on-the-fly W convert/norm + epilogue ----
// A (ne) staged via global_load_lds (already bf16); B staged fp32->bf16 in registers
// with per-column sum-of-squares accumulated during staging. Epilogue multiplies by
// rsqrt(|w|^2) before clip/masks. XCD-swizzled block order keeps a B col-tile's 8
// row-tiles on one XCD so B is fetched from HBM once per XCD.
__global__ __launch_bounds__(256, 3)
void k_gemm(const unsigned short* __restrict__ A,   // ne [1024][512] bf16
            const float* __restrict__ W,            // raw weight [100000][512] fp32
            const float* __restrict__ ftl, const float* __restrict__ ftl1,
            const int* __restrict__ labels,
            float* __restrict__ out, unsigned* __restrict__ cnt) {
    __shared__ unsigned short ldsA[2 * 128 * 32];   // double-buffered [128][32]
    __shared__ unsigned short ldsB[2 * 128 * 32];
    __shared__ float sF[128], sF1[128], sInvW[128];
    __shared__ int sLab[128];
    __shared__ unsigned sCnt[8];

    const int tid = threadIdx.x;
    // bijective XCD swizzle: flat%8 = XCD (round-robin). Give each XCD a
    // contiguous run of col-tiles with all 8 row-tiles -> B panel hits one L2.
    const int flat = blockIdx.x;
    const int p = (flat & 7) * NCOL_TILES + (flat >> 3);
    const int rowBase = (p & 7) * 128;      // 8 row tiles
    const int colBase = (p >> 3) * 128;     // 782 col tiles

    if (tid < 128) {
        sF[tid]  = ftl[rowBase + tid];
        sF1[tid] = ftl1[rowBase + tid];
        sLab[tid] = labels[rowBase + tid];
    }

    const int wave = tid >> 6;
    const int lane = tid & 63;
    const int wm = wave >> 1, wn = wave & 1;

    // A staging (global_load_lds, linear dest): thread tid -> row tid/4, k-chunk (tid&3)*8
    const unsigned short* gA = A + (size_t)(rowBase + (tid >> 2)) * EMB + (tid & 3) * 8;

    // B staging: 4 chunks/thread, chunk c covers element e = c*256+tid of the
    // 128x(32/4) float4 grid: row = e>>3, k4 = e&7. Fully coalesced 1KB/wave/instr.
    const float* gW[4];
    #pragma unroll
    for (int c = 0; c < 4; c++) {
        int e = c * 256 + tid;
        int wr = colBase + (e >> 3);
        if (wr >= NUM_CLASS) wr = NUM_CLASS - 1;   // clamp OOB tail rows (discarded)
        gW[c] = W + (size_t)wr * EMB + (e & 7) * 4;
    }

    const int rA = (wm * 64 + (lane & 15)) * 32 + (lane >> 4) * 8;
    const int rB = (wn * 64 + (lane & 15)) * 32 + (lane >> 4) * 8;

    floatx4 acc[4][4] = {};
    float ssc[4] = {0.f, 0.f, 0.f, 0.f};
    float4 bv[4];

    // prologue: prefetch K-step 0 into buffer 0 / registers
    #pragma unroll
    for (int c = 0; c < 4; c++) bv[c] = *(const float4*)(gW[c]);
    load16(gA, &ldsA[tid * 8]);
    load16(gA + 64 * EMB, &ldsA[2048 + tid * 8]);

    #pragma unroll 2
    for (int kk = 0; kk < EMB; kk += 32) {
        const int curo = (kk & 32) << 7;           // 0 / 4096 elements, alternating
        // convert fp32->bf16, accumulate |w|^2, write current B tile
        #pragma unroll
        for (int c = 0; c < 4; c++) {
            float4 f = bv[c];
            ssc[c] += f.x * f.x + f.y * f.y + f.z * f.z + f.w * f.w;
            uint2 pw;
            pw.x = (unsigned)f2bf(f.x) | ((unsigned)f2bf(f.y) << 16);
            pw.y = (unsigned)f2bf(f.z) | ((unsigned)f2bf(f.w) << 16);
            *(uint2*)&ldsB[curo + (c * 256 + tid) * 4] = pw;
        }
        __syncthreads();   // drains A load_lds for this buffer + publishes ds_writes
        if (kk + 32 < EMB) {
            const int nxto = curo ^ 4096;
            #pragma unroll
            for (int c = 0; c < 4; c++) bv[c] = *(const float4*)(gW[c] + kk + 32);
            load16(gA + kk + 32, &ldsA[nxto + tid * 8]);
            load16(gA + kk + 32 + 64 * EMB, &ldsA[nxto + 2048 + tid * 8]);
        }
        bf16x8 af[4], bf[4];
        #pragma unroll
        for (int mi = 0; mi < 4; mi++) af[mi] = *(const bf16x8*)&ldsA[curo + rA + mi * 512];
        #pragma unroll
        for (int ni = 0; ni < 4; ni++) bf[ni] = *(const bf16x8*)&ldsB[curo + rB + ni * 512];
        // swapped operands: lane&15 = batch row, (lane>>4)*4 + r = class col
        #pragma unroll
        for (int mi = 0; mi < 4; mi++)
            #pragma unroll
            for (int ni = 0; ni < 4; ni++)
                acc[mi][ni] = __builtin_amdgcn_mfma_f32_16x16x32_bf16(bf[ni], af[mi], acc[mi][ni], 0, 0, 0);
    }

    // finalize 1/|w| per column: row r's 8 half-row partials live in 8 adjacent lanes
    #pragma unroll
    for (int c = 0; c < 4; c++) {
        float ss = ssc[c];
        ss += __shfl_xor(ss, 1);
        ss += __shfl_xor(ss, 2);
        ss += __shfl_xor(ss, 4);
        if ((tid & 7) == 0) sInvW[(c * 256 + tid) >> 3] = rsqrtf(ss);
    }
    __syncthreads();

    // epilogue: normalize, clip, masks, counts, label override, scale, nt store
    unsigned cH = 0, cN = 0;
    #pragma unroll
    for (int mi = 0; mi < 4; mi++) {
        const int row = wm * 64 + mi * 16 + (lane & 15);
        const float F = sF[row], F1 = sF1[row];
        const int lab = sLab[row];
        float* orow = out + (size_t)(rowBase + row) * NUM_CLASS;
        #pragma unroll
        for (int ni = 0; ni < 4; ni++) {
            const int colL = wn * 64 + ni * 16 + (lane >> 4) * 4;
            const int col = colBase + colL;
            if (col < NUM_CLASS) {     // 100000 % 4 == 0: chunk fully in or out
                floatx4 a = acc[mi][ni];
                const float* iw = &sInvW[colL];
                floatx4 v;
                #pragma unroll
                for (int r = 0; r < 4; r++) {
                    float lg = fminf(1.0f, fmaxf(-1.0f, a[r] * iw[r]));
                    bool h = lg > F, n = lg > F1;
                    cH += h; cN += n;
                    float val = n ? fmaxf(lg, 1e-30f) : (h ? lg * T_HARD : lg);
                    if (col + r == lab) val = F;
                    v[r] = val * S_SCALE;
                }
                __builtin_nontemporal_store(v, (floatx4*)(orow + col));
            }
        }
    }
    for (int off = 32; off; off >>= 1) { cH += __shfl_down(cH, off); cN += __shfl_down(cN, off); }
    if (lane == 0) { sCnt[wave] = cH; sCnt[4 + wave] = cN; }
    __syncthreads();
    if (tid == 0) {
        unsigned h = sCnt[0] + sCnt[1] + sCnt[2] + sCnt[3];
        unsigned n = sCnt[4] + sCnt[5] + sCnt[6] + sCnt[7];
        atomicAdd(&cnt[0], h);
        atomicAdd(&cnt[1], n);
        __threadfence();
        // last block finalizes the scalar outputs (replaces k_final launch)
        if (atomicAdd(&cnt[2], 1u) == (unsigned)(GRID_X - 1)) {
            unsigned hard_cnt = atomicAdd(&cnt[0], 0u);
            unsigned noise_num = atomicAdd(&cnt[1], 0u);
            const unsigned num_all = (unsigned)BATCH * (unsigned)NUM_CLASS; // 102,400,000
            unsigned easy = num_all - hard_cnt;
            float* o = out + (size_t)BATCH * NUM_CLASS;
            o[0] = (float)easy;
            o[1] = (float)noise_num;
            o[2] = (float)(hard_cnt - noise_num);
            o[3] = ((float)easy / (float)num_all) * 0.01f;
        }
    }
}

extern "C" void kernel_launch(void* const* d_in, const int* in_sizes, int n_in,
                              void* d_out, int out_size, void* d_ws, size_t ws_size,
                              hipStream_t stream) {
    const float* emb = (const float*)d_in[0];
    const float* wgt = (const float*)d_in[1];
    const int* labels = (const int*)d_in[2];
    float* out = (float*)d_out;
    char* ws = (char*)d_ws;

    unsigned* cnt = (unsigned*)ws;                           // 64 B (incl. ticket)
    float* ftl  = (float*)(ws + 64);                         // 4 KB
    float* ftl1 = (float*)(ws + 8192);                       // 4 KB
    unsigned short* ne = (unsigned short*)(ws + 16384);      // 1 MB

    hipMemsetAsync(cnt, 0, 64, stream);
    k_embed<<<BATCH, 256, 0, stream>>>(emb, ne);
    k_tl<<<BATCH / 4, 256, 0, stream>>>(ne, wgt, labels, ftl, ftl1);
    k_gemm<<<GRID_X, 256, 0, stream>>>(ne, wgt, ftl, ftl1, labels, out, cnt);
}